// Round 8
// baseline (171.468 us; speedup 1.0000x reference)
//
#include <hip/hip_runtime.h>

#define N_NODES 100000
#define N_EDGES 2500000
#define NQ4 625000             // N_EDGES/4 int4 chunks
#define SBBITS 11
#define SBSZ 2048              // nodes per superbucket
#define NSB 49                 // ceil(N_NODES/2048)
#define SB 512                 // edge-chunk blocks for hist/scatter
#define EPB4 1221              // int4 chunks per block (ceil(NQ4/SB))
#define TOT (NSB * SB)         // 25088 (sb-major, block-minor)
#define M 16                   // agg blocks per superbucket
#define AGG_GRID (NSB * M)     // 784

// pass-1 fixed point: (x+16)*2^16; u32 sum ok; signed debias via (int) [R6-validated]
// pass-2 fixed point: (h2+2048)*2^12; signed debias via (int)          [R6-validated]

typedef unsigned int u32;
typedef unsigned long long u64;

// ---------------------------------------------------------------------------
// S1: per-(superbucket, block) histogram. int4 dst reads, 8-way LDS replicas.
// ---------------------------------------------------------------------------
__global__ void hist_k(const int* __restrict__ ei, u32* __restrict__ histG) {
    __shared__ u32 hl[NSB * 8];
    int t = threadIdx.x, b = blockIdx.x;
    for (int k = t; k < NSB * 8; k += 256) hl[k] = 0;
    __syncthreads();
    const int4* d4 = (const int4*)(ei + N_EDGES);
    int q0 = b * EPB4, q1 = min(q0 + EPB4, NQ4);
    int r = t & 7;
    for (int q = q0 + t; q < q1; q += 256) {
        int4 d = d4[q];
        atomicAdd(&hl[((u32)d.x >> SBBITS) * 8 + r], 1u);
        atomicAdd(&hl[((u32)d.y >> SBBITS) * 8 + r], 1u);
        atomicAdd(&hl[((u32)d.z >> SBBITS) * 8 + r], 1u);
        atomicAdd(&hl[((u32)d.w >> SBBITS) * 8 + r], 1u);
    }
    __syncthreads();
    for (int k = t; k < NSB; k += 256) {
        u32 s = 0;
#pragma unroll
        for (int j = 0; j < 8; ++j) s += hl[k * 8 + j];
        histG[k * SB + b] = s;
    }
}

// ---------------------------------------------------------------------------
// P: single-block exclusive scan of histG[TOT] in place.
// Each of 1024 threads owns a 25-element chunk; LDS scan of thread sums.
// ---------------------------------------------------------------------------
__global__ void scan_all(u32* histG) {
    __shared__ u32 ts[1024];
    int t = threadIdx.x;
    int start = t * 25;
    u32 s = 0;
#pragma unroll
    for (int j = 0; j < 25; ++j) {
        int idx = start + j;
        if (idx < TOT) s += histG[idx];
    }
    ts[t] = s;
    __syncthreads();
    for (int off = 1; off < 1024; off <<= 1) {
        u32 add = (t >= off) ? ts[t - off] : 0u;
        __syncthreads();
        ts[t] += add;
        __syncthreads();
    }
    u32 run = (t > 0) ? ts[t - 1] : 0u;
#pragma unroll
    for (int j = 0; j < 25; ++j) {
        int idx = start + j;
        if (idx < TOT) {
            u32 x = histG[idx];   // chunk is thread-exclusive: safe in-place
            histG[idx] = run;
            run += x;
        }
    }
}

// ---------------------------------------------------------------------------
// S3: scatter edges into superbucket order. int4 src/dst reads.
// Packed edge: (dst&2047)<<17 | src
// ---------------------------------------------------------------------------
__global__ void scatter_k(const int* __restrict__ ei, const u32* __restrict__ histG,
                          u32* __restrict__ sortedE) {
    __shared__ u32 pos[NSB];
    int t = threadIdx.x, b = blockIdx.x;
    if (t < NSB) pos[t] = histG[t * SB + b];
    __syncthreads();
    const int4* s4 = (const int4*)ei;
    const int4* d4 = (const int4*)(ei + N_EDGES);
    int q0 = b * EPB4, q1 = min(q0 + EPB4, NQ4);
    for (int q = q0 + t; q < q1; q += 256) {
        int4 sv = s4[q];
        int4 dv = d4[q];
        u32 slot;
        slot = atomicAdd(&pos[(u32)dv.x >> SBBITS], 1u);
        sortedE[slot] = (((u32)dv.x & (SBSZ - 1u)) << 17) | (u32)sv.x;
        slot = atomicAdd(&pos[(u32)dv.y >> SBBITS], 1u);
        sortedE[slot] = (((u32)dv.y & (SBSZ - 1u)) << 17) | (u32)sv.y;
        slot = atomicAdd(&pos[(u32)dv.z >> SBBITS], 1u);
        sortedE[slot] = (((u32)dv.z & (SBSZ - 1u)) << 17) | (u32)sv.z;
        slot = atomicAdd(&pos[(u32)dv.w >> SBBITS], 1u);
        sortedE[slot] = (((u32)dv.w & (SBSZ - 1u)) << 17) | (u32)sv.w;
    }
}

// ---------------------------------------------------------------------------
// A1: partial aggregation of x over one superbucket slice (4-way gather ILP).
// ---------------------------------------------------------------------------
__global__ void agg1_k(const u32* __restrict__ sortedE, const u32* __restrict__ histG,
                       const float* __restrict__ x, u32* __restrict__ PART) {
    __shared__ u32 cntL[SBSZ], fxL[SBSZ], fyL[SBSZ];
    int t = threadIdx.x;
    u32 sb = blockIdx.x / M, m = blockIdx.x % M;
    for (int j = t; j < SBSZ; j += 256) { cntL[j] = 0; fxL[j] = 0; fyL[j] = 0; }
    __syncthreads();

    u32 s0 = histG[sb * SB];
    u32 s1 = (sb + 1 < NSB) ? histG[(sb + 1) * SB] : N_EDGES;
    u32 len = s1 - s0;
    u32 a = s0 + len * m / M;
    u32 bEnd = s0 + len * (m + 1) / M;
    const float2* x2 = (const float2*)x;

    u32 idx = a + t;
    while (idx + 768 < bEnd) {
        u32 p0 = sortedE[idx], p1 = sortedE[idx + 256];
        u32 p2 = sortedE[idx + 512], p3 = sortedE[idx + 768];
        float2 v0 = x2[p0 & 0x1FFFFu];
        float2 v1 = x2[p1 & 0x1FFFFu];
        float2 v2 = x2[p2 & 0x1FFFFu];
        float2 v3 = x2[p3 & 0x1FFFFu];
        u32 l0 = p0 >> 17, l1 = p1 >> 17, l2 = p2 >> 17, l3 = p3 >> 17;
        atomicAdd(&cntL[l0], 1u);
        atomicAdd(&fxL[l0], (u32)((v0.x + 16.0f) * 65536.0f + 0.5f));
        atomicAdd(&fyL[l0], (u32)((v0.y + 16.0f) * 65536.0f + 0.5f));
        atomicAdd(&cntL[l1], 1u);
        atomicAdd(&fxL[l1], (u32)((v1.x + 16.0f) * 65536.0f + 0.5f));
        atomicAdd(&fyL[l1], (u32)((v1.y + 16.0f) * 65536.0f + 0.5f));
        atomicAdd(&cntL[l2], 1u);
        atomicAdd(&fxL[l2], (u32)((v2.x + 16.0f) * 65536.0f + 0.5f));
        atomicAdd(&fyL[l2], (u32)((v2.y + 16.0f) * 65536.0f + 0.5f));
        atomicAdd(&cntL[l3], 1u);
        atomicAdd(&fxL[l3], (u32)((v3.x + 16.0f) * 65536.0f + 0.5f));
        atomicAdd(&fyL[l3], (u32)((v3.y + 16.0f) * 65536.0f + 0.5f));
        idx += 1024;
    }
    while (idx < bEnd) {
        u32 p = sortedE[idx];
        float2 v = x2[p & 0x1FFFFu];
        u32 l = p >> 17;
        atomicAdd(&cntL[l], 1u);
        atomicAdd(&fxL[l], (u32)((v.x + 16.0f) * 65536.0f + 0.5f));
        atomicAdd(&fyL[l], (u32)((v.y + 16.0f) * 65536.0f + 0.5f));
        idx += 256;
    }
    __syncthreads();

    u32 base = blockIdx.x * (3 * SBSZ);
    for (int j = t; j < SBSZ; j += 256) {
        PART[base + j] = cntL[j];
        PART[base + SBSZ + j] = fxL[j];
        PART[base + 2 * SBSZ + j] = fyL[j];
    }
}

// ---------------------------------------------------------------------------
// R1: sum M partials per node, decode, fused node layer 1.
// ---------------------------------------------------------------------------
__global__ void reduce1_node1(const u32* __restrict__ PART, const float* __restrict__ x,
                              const float* __restrict__ Wl1, const float* __restrict__ Wr1,
                              const float* __restrict__ b1,
                              const float* __restrict__ Wl2, const float* __restrict__ Wr2,
                              u64* __restrict__ ench2, float2* __restrict__ hrG,
                              float* __restrict__ degG) {
    __shared__ float sWl1[64], sWr1[64], sb1[32], sWl2[64], sWr2[64];
    int t = threadIdx.x;
    if (t < 64) { sWl1[t] = Wl1[t]; sWr1[t] = Wr1[t]; sWl2[t] = Wl2[t]; sWr2[t] = Wr2[t]; }
    if (t >= 64 && t < 96) sb1[t - 64] = b1[t - 64];
    __syncthreads();

    int i = blockIdx.x * 256 + t;
    if (i >= N_NODES) return;
    u32 sb = (u32)i >> SBBITS, j = (u32)i & (SBSZ - 1u);

    u32 cnt = 0, fx = 0, fy = 0;
#pragma unroll
    for (int m = 0; m < M; ++m) {
        u32 base = (sb * M + m) * (3 * SBSZ);
        cnt += PART[base + j];
        fx += PART[base + SBSZ + j];
        fy += PART[base + 2 * SBSZ + j];
    }

    float fc = (float)cnt;
    float dinv = 1.0f / fmaxf(fc, 1.0f);
    float ax = (float)(int)(fx - cnt * 1048576u) * (1.0f / 65536.0f) * dinv;
    float ay = (float)(int)(fy - cnt * 1048576u) * (1.0f / 65536.0f) * dinv;
    float2 xv = ((const float2*)x)[i];

    float h2a = 0.f, h2b = 0.f, hra = 0.f, hrb = 0.f;
#pragma unroll
    for (int f = 0; f < 32; ++f) {
        float h = ax * sWl1[f] + ay * sWl1[32 + f] + xv.x * sWr1[f] + xv.y * sWr1[32 + f] + sb1[f];
        h = fmaxf(h, 0.0f);
        h2a += h * sWl2[2 * f];
        h2b += h * sWl2[2 * f + 1];
        hra += h * sWr2[2 * f];
        hrb += h * sWr2[2 * f + 1];
    }
    u32 ex = (u32)((h2a + 2048.0f) * 4096.0f + 0.5f);
    u32 ey = (u32)((h2b + 2048.0f) * 4096.0f + 0.5f);
    ench2[i] = ((u64)ey << 32) | (u64)ex;
    hrG[i] = make_float2(hra, hrb);
    degG[i] = fc;
}

// ---------------------------------------------------------------------------
// A2: partial aggregation of encoded h2 (4-way gather ILP).
// ---------------------------------------------------------------------------
__global__ void agg2_k(const u32* __restrict__ sortedE, const u32* __restrict__ histG,
                       const u64* __restrict__ ench2, u32* __restrict__ PART2) {
    __shared__ u32 gxL[SBSZ], gyL[SBSZ];
    int t = threadIdx.x;
    u32 sb = blockIdx.x / M, m = blockIdx.x % M;
    for (int j = t; j < SBSZ; j += 256) { gxL[j] = 0; gyL[j] = 0; }
    __syncthreads();

    u32 s0 = histG[sb * SB];
    u32 s1 = (sb + 1 < NSB) ? histG[(sb + 1) * SB] : N_EDGES;
    u32 len = s1 - s0;
    u32 a = s0 + len * m / M;
    u32 bEnd = s0 + len * (m + 1) / M;

    u32 idx = a + t;
    while (idx + 768 < bEnd) {
        u32 p0 = sortedE[idx], p1 = sortedE[idx + 256];
        u32 p2 = sortedE[idx + 512], p3 = sortedE[idx + 768];
        u64 e0 = ench2[p0 & 0x1FFFFu];
        u64 e1 = ench2[p1 & 0x1FFFFu];
        u64 e2 = ench2[p2 & 0x1FFFFu];
        u64 e3 = ench2[p3 & 0x1FFFFu];
        u32 l0 = p0 >> 17, l1 = p1 >> 17, l2 = p2 >> 17, l3 = p3 >> 17;
        atomicAdd(&gxL[l0], (u32)e0); atomicAdd(&gyL[l0], (u32)(e0 >> 32));
        atomicAdd(&gxL[l1], (u32)e1); atomicAdd(&gyL[l1], (u32)(e1 >> 32));
        atomicAdd(&gxL[l2], (u32)e2); atomicAdd(&gyL[l2], (u32)(e2 >> 32));
        atomicAdd(&gxL[l3], (u32)e3); atomicAdd(&gyL[l3], (u32)(e3 >> 32));
        idx += 1024;
    }
    while (idx < bEnd) {
        u32 p = sortedE[idx];
        u64 e = ench2[p & 0x1FFFFu];
        u32 l = p >> 17;
        atomicAdd(&gxL[l], (u32)e);
        atomicAdd(&gyL[l], (u32)(e >> 32));
        idx += 256;
    }
    __syncthreads();

    u32 base = blockIdx.x * (2 * SBSZ);
    for (int j = t; j < SBSZ; j += 256) {
        PART2[base + j] = gxL[j];
        PART2[base + SBSZ + j] = gyL[j];
    }
}

// ---------------------------------------------------------------------------
// R2: sum M partials, decode, combine with hr + b2, log_softmax.
// ---------------------------------------------------------------------------
__global__ void reduce2_node2(const u32* __restrict__ PART2, const float2* __restrict__ hrG,
                              const float* __restrict__ degG, const float* __restrict__ b2,
                              float* __restrict__ out) {
    int i = blockIdx.x * 256 + threadIdx.x;
    if (i >= N_NODES) return;
    u32 sb = (u32)i >> SBBITS, j = (u32)i & (SBSZ - 1u);

    u32 gx = 0, gy = 0;
#pragma unroll
    for (int m = 0; m < M; ++m) {
        u32 base = (sb * M + m) * (2 * SBSZ);
        gx += PART2[base + j];
        gy += PART2[base + SBSZ + j];
    }

    float fc = degG[i];
    u32 c = (u32)fc;
    float dinv = 1.0f / fmaxf(fc, 1.0f);
    float sx = (float)(int)(gx - c * 8388608u) * (1.0f / 4096.0f) * dinv;
    float sy = (float)(int)(gy - c * 8388608u) * (1.0f / 4096.0f) * dinv;
    float2 hv = hrG[i];
    float o0 = sx + hv.x + b2[0];
    float o1 = sy + hv.y + b2[1];
    float mx = fmaxf(o0, o1);
    float e0 = expf(o0 - mx);
    float e1 = expf(o1 - mx);
    float lse = logf(e0 + e1);
    ((float2*)out)[i] = make_float2(o0 - mx - lse, o1 - mx - lse);
}

extern "C" void kernel_launch(void* const* d_in, const int* in_sizes, int n_in,
                              void* d_out, int out_size, void* d_ws, size_t ws_size,
                              hipStream_t stream) {
    const float* x   = (const float*)d_in[0];
    const int*   ei  = (const int*)d_in[1];
    const float* Wl1 = (const float*)d_in[2];
    const float* Wr1 = (const float*)d_in[3];
    const float* b1  = (const float*)d_in[4];
    const float* Wl2 = (const float*)d_in[5];
    const float* Wr2 = (const float*)d_in[6];
    const float* b2  = (const float*)d_in[7];
    float* out = (float*)d_out;

    u32* histG   = (u32*)d_ws;               // [25088], scanned in place
    u32* sortedE = histG + TOT;              // [2.5M]
    u32* PART    = sortedE + N_EDGES;        // [784*6144] = 19.3 MB (PART2 aliased)
    u64* ench2   = (u64*)(PART + AGG_GRID * 3 * SBSZ);   // [N] u64
    float2* hrG  = (float2*)(ench2 + N_NODES);           // [N]
    float* degG  = (float*)(hrG + N_NODES);              // [N]
    // total ws use ~31.3 MB

    hist_k   <<<SB, 256, 0, stream>>>(ei, histG);
    scan_all <<<1, 1024, 0, stream>>>(histG);
    scatter_k<<<SB, 256, 0, stream>>>(ei, histG, sortedE);
    agg1_k   <<<AGG_GRID, 256, 0, stream>>>(sortedE, histG, x, PART);
    reduce1_node1<<<(N_NODES + 255) / 256, 256, 0, stream>>>(PART, x, Wl1, Wr1, b1,
                                                             Wl2, Wr2, ench2, hrG, degG);
    agg2_k   <<<AGG_GRID, 256, 0, stream>>>(sortedE, histG, ench2, PART);
    reduce2_node2<<<(N_NODES + 255) / 256, 256, 0, stream>>>(PART, hrG, degG, b2, out);
}